// Round 4
// baseline (369.916 us; speedup 1.0000x reference)
//
#include <hip/hip_runtime.h>

#define DEVFN __device__ __forceinline__

namespace {
constexpr int B    = 512;
constexpr int D    = 200;
constexpr int RNUM = 200;
constexpr int REL  = 1800;
constexpr int FH   = 58, FW = 18, NP = FH * FW;     // 1044
constexpr int IMH  = 60, IMW = 20, IMN = IMH * IMW; // 1200
constexpr float EPS = 1e-5f;
constexpr float INV_SQRT_D = 0.07071067811865475f;  // 1/sqrt(200)

// k_kv split
constexpr int RB = 8;   // rows per block
constexpr int CH = 8;   // REL chunks
constexpr int CLEN = REL / CH;  // 225

// workspace layout (float offsets)
constexpr int OFF_X    = 0;                      // B*IMN  conv image (bn0'd)
constexpr int OFF_EM   = OFF_X   + B * IMN;      // B*D
constexpr int OFF_R    = OFF_EM  + B * D;        // B*REL
constexpr int OFF_W    = OFF_R   + B * REL;      // B*REL  bn2(r)
constexpr int OFF_Q    = OFF_W   + B * REL;      // B*D
constexpr int OFF_K    = OFF_Q   + B * D;        // B*D    K TRANSPOSED: kT[d][b]
constexpr int OFF_V    = OFF_K   + B * D;        // B*D    V normal: v[b][d]
constexpr int OFF_ATT  = OFF_V   + B * D;        // B*D
constexpr int OFF_S    = OFF_ATT + B * D;        // B*9
constexpr int OFF_G    = OFF_S   + B * 9;        // B*45
constexpr int OFF_BN0P = OFF_G   + B * 45;       // 96 = 6 slots * 8 chunks * {sum,sq}
constexpr int OFF_BN2M = OFF_BN0P + 96;          // REL
constexpr int OFF_BN2S = OFF_BN2M + REL;         // REL
constexpr int OFF_BN1M = OFF_BN2S + REL;         // RNUM
constexpr int OFF_BN1S = OFF_BN1M + RNUM;        // RNUM
constexpr int OFF_WP   = OFF_BN1S + RNUM;        // NP
constexpr int OFF_BP   = OFF_WP  + NP;           // 1
} // namespace

DEVFN float waveSum(float v) {
#pragma unroll
  for (int o = 32; o; o >>= 1) v += __shfl_down(v, o, 64);
  return v;
}
DEVFN float waveMax(float v) {
#pragma unroll
  for (int o = 32; o; o >>= 1) v = fmaxf(v, __shfl_down(v, o, 64));
  return v;
}
DEVFN float blockSum256(float v, float* sm) {
  int lane = threadIdx.x & 63, w = threadIdx.x >> 6;
  v = waveSum(v);
  if (lane == 0) sm[w] = v;
  __syncthreads();
  if (threadIdx.x == 0) sm[4] = sm[0] + sm[1] + sm[2] + sm[3];
  __syncthreads();
  float t = sm[4];
  __syncthreads();
  return t;
}
DEVFN float blockMax256(float v, float* sm) {
  int lane = threadIdx.x & 63, w = threadIdx.x >> 6;
  v = waveMax(v);
  if (lane == 0) sm[w] = v;
  __syncthreads();
  if (threadIdx.x == 0) sm[4] = fmaxf(fmaxf(sm[0], sm[1]), fmaxf(sm[2], sm[3]));
  __syncthreads();
  float t = sm[4];
  __syncthreads();
  return t;
}
DEVFN float blockSum384(float v, float* sm) {
  int lane = threadIdx.x & 63, w = threadIdx.x >> 6;  // 0..5
  v = waveSum(v);
  if (lane == 0) sm[w] = v;
  __syncthreads();
  if (threadIdx.x == 0) sm[6] = sm[0] + sm[1] + sm[2] + sm[3] + sm[4] + sm[5];
  __syncthreads();
  float t = sm[6];
  __syncthreads();
  return t;
}

// =============== MEGA 1: gather_bn0(48) | gather_r(512) | zero K/V(800) | wp(5) ===============
__global__ __launch_bounds__(256) void mega1(
    const int* i1, const int* i2, const int* i3, const int* i4, const int* i5,
    const int* i6, const int* ridx, const float* Ew, const float* Rw,
    const float* fcW, const float* fcb, const float* pv, float* ws) {
  __shared__ float red[8];
  int blk = blockIdx.x, t = threadIdx.x;
  if (blk < 48) {
    // gather entity slots + per-(slot,chunk) bn0 partial moments
    int s = blk >> 3, ch = blk & 7;
    const int* idx = (s == 0) ? i1 : (s == 1) ? i2 : (s == 2) ? i3
                   : (s == 3) ? i4 : (s == 4) ? i5 : i6;
    float sum = 0.f, sq = 0.f;
    for (int ii = t; ii < 64 * D; ii += 256) {
      int b = ch * 64 + ii / D, d = ii % D;
      float v = Ew[(long long)idx[b] * D + d];
      ws[OFF_X + b * IMN + s * D + d] = v;
      sum += v; sq += v * v;
    }
    float ts = blockSum256(sum, red);
    float tq = blockSum256(sq, red);
    if (t == 0) {
      ws[OFF_BN0P + (s * 8 + ch) * 2]     = ts;
      ws[OFF_BN0P + (s * 8 + ch) * 2 + 1] = tq;
    }
  } else if (blk < 560) {
    // gather relation rows, float4
    int b = blk - 48;
    const float4* src = (const float4*)(Rw + (long long)ridx[b] * REL);
    float4* dst = (float4*)(ws + OFF_R + b * REL);
    for (int c = t; c < REL / 4; c += 256) dst[c] = src[c];
  } else if (blk < 1360) {
    // zero K/V accumulators (contiguous 2*B*D floats)
    int i = (blk - 560) * 256 + t;
    ws[OFF_K + i] = 0.f;
  } else {
    // wp = fc6_W^T @ p, bp = fc6_b . p
    int p = (blk - 1360) * 256 + t;
    if (p < NP) {
      float a = 0.f;
      for (int n = 0; n < 100; n++) a = fmaf(fcW[n * NP + p], pv[n], a);
      ws[OFF_WP + p] = a;
    } else if (p == NP) {
      float a = 0.f;
      for (int n = 0; n < 100; n++) a = fmaf(fcb[n], pv[n], a);
      ws[OFF_BP] = a;
    }
  }
}

// =============== K2: bn0 finalize+apply, e_mean, patch Gram (fused, per-b) ===============
__global__ __launch_bounds__(256) void k_bn0gram(const float* g0, const float* b0, float* ws) {
  __shared__ float img[IMN];
  __shared__ float stats[12];   // (m, invstd) x 6
  int b = blockIdx.x, t = threadIdx.x;
  if (t < 6) {
    float sum = 0.f, sq = 0.f;
#pragma unroll
    for (int ch = 0; ch < 8; ch++) {
      sum += ws[OFF_BN0P + (t * 8 + ch) * 2];
      sq  += ws[OFF_BN0P + (t * 8 + ch) * 2 + 1];
    }
    const float n = (float)(B * D);
    float m = sum / n;
    float var = sq / n - m * m;
    stats[2 * t] = m;
    stats[2 * t + 1] = rsqrtf(var + EPS);
  }
  __syncthreads();
  float g = g0[0], bb = b0[0];
  for (int i = t; i < IMN; i += 256) {
    int s = i / D;
    float v = ws[OFF_X + b * IMN + i];
    v = (v - stats[2 * s]) * stats[2 * s + 1] * g + bb;
    img[i] = v;
    ws[OFF_X + b * IMN + i] = v;
  }
  __syncthreads();
  if (t < D) {
    float acc = 0.f;
#pragma unroll
    for (int s = 0; s < 6; s++) acc += img[s * D + t];
    ws[OFF_EM + b * D + t] = acc * (1.f / 6.f);
  }
  // ---- patch moments S[9], G[45]
  float S[9]; float G[45];
#pragma unroll
  for (int a = 0; a < 9; a++) S[a] = 0.f;
#pragma unroll
  for (int u = 0; u < 45; u++) G[u] = 0.f;
  for (int p = t; p < NP; p += 256) {
    int oy = p / FW, ox = p - oy * FW;
    float tp[9];
#pragma unroll
    for (int kh = 0; kh < 3; kh++)
#pragma unroll
      for (int kw = 0; kw < 3; kw++)
        tp[kh * 3 + kw] = img[(oy + kh) * IMW + ox + kw];
    int u = 0;
#pragma unroll
    for (int a = 0; a < 9; a++) {
      S[a] += tp[a];
#pragma unroll
      for (int c = a; c < 9; c++) { G[u] += tp[a] * tp[c]; u++; }
    }
  }
#pragma unroll
  for (int a = 0; a < 9; a++) S[a] = waveSum(S[a]);
#pragma unroll
  for (int u = 0; u < 45; u++) G[u] = waveSum(G[u]);
  __shared__ float part[4][54];
  int lane = t & 63, w = t >> 6;
  if (lane == 0) {
#pragma unroll
    for (int a = 0; a < 9; a++) part[w][a] = S[a];
#pragma unroll
    for (int u = 0; u < 45; u++) part[w][9 + u] = G[u];
  }
  __syncthreads();
  if (t < 54) {
    float v = part[0][t] + part[1][t] + part[2][t] + part[3][t];
    if (t < 9) ws[OFF_S + b * 9 + t] = v;
    else       ws[OFF_G + b * 45 + (t - 9)] = v;
  }
}

// =============== MEGA 2: bn2_stats(8) | q = e_mean @ Q (400) ===============
__global__ __launch_bounds__(256) void mega2(const float* Qm, float* ws) {
  int blk = blockIdx.x, t = threadIdx.x;
  if (blk < 8) {
    int c = blk * 256 + t;
    if (c >= REL) return;
    const float* r = ws + OFF_R;
    float s = 0.f, q = 0.f;
    for (int b = 0; b < B; b++) { float v = r[b * REL + c]; s += v; q += v * v; }
    float m = s / (float)B;
    float var = q / (float)B - m * m;
    ws[OFF_BN2M + c] = m;
    ws[OFF_BN2S + c] = rsqrtf(var + EPS);
  } else {
    int i = (blk - 8) * 256 + t;
    if (i >= B * D) return;
    int b = i / D, col = i - b * D;
    const float* em = ws + OFF_EM + b * D;
    float a = 0.f;
    for (int d = 0; d < D; d++) a = fmaf(em[d], Qm[d * D + col], a);
    ws[OFF_Q + i] = a;
  }
}

// =============== MEGA 3: kv split-K (512) | bn2_apply (3600) ===============
__global__ __launch_bounds__(256) void mega3(const float* Km, const float* Vm,
                                             const float* g2, const float* b2, float* ws) {
  int blk = blockIdx.x, t = threadIdx.x;
  if (blk < 512) {
    int g = blk >> 3, ch = blk & 7;     // row-group of 8, REL chunk
    int i = t;
    if (i >= D) return;
    int c0 = ch * CLEN;
    const float* r0 = ws + OFF_R + (g * RB) * REL + c0;
    float ak[RB], av[RB];
#pragma unroll
    for (int u = 0; u < RB; u++) { ak[u] = 0.f; av[u] = 0.f; }
#pragma unroll 3
    for (int c = 0; c < CLEN; c++) {
      float km = Km[(c0 + c) * D + i], vm = Vm[(c0 + c) * D + i];
#pragma unroll
      for (int u = 0; u < RB; u++) {
        float rv = r0[u * REL + c];
        ak[u] = fmaf(rv, km, ak[u]);
        av[u] = fmaf(rv, vm, av[u]);
      }
    }
#pragma unroll
    for (int u = 0; u < RB; u++) {
      int b = g * RB + u;
      atomicAdd(&ws[OFF_K + i * B + b], ak[u]);      // K transposed kT[d][b]
      atomicAdd(&ws[OFF_V + b * D + i], av[u]);      // V normal
    }
  } else {
    int i = (blk - 512) * 256 + t;
    if (i >= B * REL) return;
    int c = i % REL;
    float v = ws[OFF_R + i];
    ws[OFF_W + i] = (v - ws[OFF_BN2M + c]) * ws[OFF_BN2S + c] * g2[c] + b2[c];
  }
}

// =============== MEGA 4: attention 2 queries/block (256) | bn1_stats (200) ===============
__global__ __launch_bounds__(256) void mega4(float* ws) {
  __shared__ float qs[2][D];
  __shared__ float sc[2][B];
  __shared__ float red[8];
  int blk = blockIdx.x, t = threadIdx.x;
  if (blk < 256) {
    int b0 = blk * 2;
    for (int i = t; i < 2 * D; i += 256) qs[i / D][i % D] = ws[OFF_Q + b0 * D + i];
    __syncthreads();
    const float* kT = ws + OFF_K;
    float lmax0 = -1e30f, lmax1 = -1e30f;
#pragma unroll
    for (int jj = 0; jj < 2; jj++) {
      int j = t + jj * 256;
      float a0 = 0.f, a1 = 0.f;
      for (int d = 0; d < D; d++) {
        float kv = kT[d * B + j];
        a0 = fmaf(qs[0][d], kv, a0);
        a1 = fmaf(qs[1][d], kv, a1);
      }
      a0 *= INV_SQRT_D; a1 *= INV_SQRT_D;
      sc[0][j] = a0; sc[1][j] = a1;
      lmax0 = fmaxf(lmax0, a0); lmax1 = fmaxf(lmax1, a1);
    }
    float gmax0 = blockMax256(lmax0, red);
    float gmax1 = blockMax256(lmax1, red);
    float lsum0 = 0.f, lsum1 = 0.f;
#pragma unroll
    for (int jj = 0; jj < 2; jj++) {
      int j = t + jj * 256;
      float e0 = __expf(sc[0][j] - gmax0);
      float e1 = __expf(sc[1][j] - gmax1);
      sc[0][j] = e0; sc[1][j] = e1;
      lsum0 += e0; lsum1 += e1;
    }
    float tot0 = blockSum256(lsum0, red);
    float tot1 = blockSum256(lsum1, red);
    float inv0 = 1.f / tot0, inv1 = 1.f / tot1;
    if (t < D) {
      const float* v = ws + OFF_V;
      float a0 = 0.f, a1 = 0.f;
#pragma unroll 4
      for (int j = 0; j < B; j++) {
        float vv = v[j * D + t];
        a0 = fmaf(sc[0][j], vv, a0);
        a1 = fmaf(sc[1][j], vv, a1);
      }
      ws[OFF_ATT + b0 * D + t]       = a0 * inv0;
      ws[OFF_ATT + (b0 + 1) * D + t] = a1 * inv1;
    }
  } else {
    // bn1 stats via Gram trick: sum_y = w.S ; sumsq_y = w'Gw
    int j = blk - 256;
    float s = 0.f, q = 0.f;
    for (int b = t; b < B; b += 256) {
      const float* w9 = ws + OFF_W + b * REL + j * 9;
      float wr[9];
#pragma unroll
      for (int k = 0; k < 9; k++) wr[k] = w9[k];
      const float* Sb = ws + OFF_S + b * 9;
      const float* Gb = ws + OFF_G + b * 45;
      float sl = 0.f;
#pragma unroll
      for (int k = 0; k < 9; k++) sl = fmaf(wr[k], Sb[k], sl);
      float ql = 0.f;
      int u = 0;
#pragma unroll
      for (int a = 0; a < 9; a++) {
        ql = fmaf(wr[a] * wr[a], Gb[u], ql); u++;
#pragma unroll
        for (int c = a + 1; c < 9; c++) { ql = fmaf(2.f * wr[a] * wr[c], Gb[u], ql); u++; }
      }
      s += sl; q += ql;
    }
    float ts = blockSum256(s, red);
    float tq = blockSum256(q, red);
    if (t == 0) {
      const float N = (float)B * (float)NP;
      float m = ts / N;
      float var = tq / N - m * m;
      ws[OFF_BN1M + j] = m;
      ws[OFF_BN1S + j] = rsqrtf(var + EPS);
    }
  }
}

// =============== K6: final fused conv+BN1+relu+att+fc (384 thr, packed params) ===============
__global__ __launch_bounds__(384) void k_final(const float* g1, const float* b1,
                                               float* ws, float* out) {
  __shared__ float img[IMN];
  __shared__ float wpl[NP];
  __shared__ float packed[RNUM * 12];   // [w0..w8]*sc, bb, aj, pad
  __shared__ float red[8];
  int b = blockIdx.x, t = threadIdx.x;
  for (int i = t; i < IMN; i += 384) img[i] = ws[OFF_X + b * IMN + i];
  for (int i = t; i < NP; i += 384) wpl[i] = ws[OFF_WP + i];
  if (t < RNUM) {
    int j = t;
    float m = ws[OFF_BN1M + j], is = ws[OFF_BN1S + j];
    float sc = is * g1[j];
    float bb = b1[j] - m * sc;
    const float* w9 = ws + OFF_W + b * REL + j * 9;
#pragma unroll
    for (int k = 0; k < 9; k++) packed[j * 12 + k] = w9[k] * sc;
    packed[j * 12 + 9]  = bb;
    packed[j * 12 + 10] = ws[OFF_ATT + b * D + j];
    packed[j * 12 + 11] = 0.f;
  }
  __syncthreads();
  float taps[3][9];
  float wv[3];
#pragma unroll
  for (int pp = 0; pp < 3; pp++) {
    int p = t + pp * 384;
    bool ok = (p < NP);
    int pc = ok ? p : 0;
    int oy = pc / FW, ox = pc - oy * FW;
#pragma unroll
    for (int kh = 0; kh < 3; kh++)
#pragma unroll
      for (int kw = 0; kw < 3; kw++)
        taps[pp][kh * 3 + kw] = img[(oy + kh) * IMW + ox + kw];
    wv[pp] = ok ? wpl[p] : 0.f;
  }
  float acc = 0.f;
  for (int j = 0; j < RNUM; j++) {
    const float4* rec = (const float4*)&packed[j * 12];
    float4 r0 = rec[0], r1 = rec[1], r2 = rec[2];
    float zs = 0.f;
#pragma unroll
    for (int pp = 0; pp < 3; pp++) {
      float y = r2.y;  // bb
      y = fmaf(taps[pp][0], r0.x, y);
      y = fmaf(taps[pp][1], r0.y, y);
      y = fmaf(taps[pp][2], r0.z, y);
      y = fmaf(taps[pp][3], r0.w, y);
      y = fmaf(taps[pp][4], r1.x, y);
      y = fmaf(taps[pp][5], r1.y, y);
      y = fmaf(taps[pp][6], r1.z, y);
      y = fmaf(taps[pp][7], r1.w, y);
      y = fmaf(taps[pp][8], r2.x, y);
      float z = fmaxf(y, 0.f);
      zs = fmaf(z, wv[pp], zs);
    }
    acc = fmaf(zs, r2.z, acc);  // * aj
  }
  float tot = blockSum384(acc, red);
  if (t == 0) out[b] = tot + ws[OFF_BP];
}

extern "C" void kernel_launch(void* const* d_in, const int* in_sizes, int n_in,
                              void* d_out, int out_size, void* d_ws, size_t ws_size,
                              hipStream_t stream) {
  const int*   r_idx = (const int*)d_in[0];
  const int*   e1 = (const int*)d_in[1];
  const int*   e2 = (const int*)d_in[2];
  const int*   e3 = (const int*)d_in[3];
  const int*   e4 = (const int*)d_in[4];
  const int*   e5 = (const int*)d_in[5];
  const int*   e6 = (const int*)d_in[6];
  const float* E_w  = (const float*)d_in[7];
  const float* R_w  = (const float*)d_in[8];
  const float* bn0g = (const float*)d_in[9];
  const float* bn0b = (const float*)d_in[10];
  const float* bn1g = (const float*)d_in[11];
  const float* bn1b = (const float*)d_in[12];
  const float* bn2g = (const float*)d_in[13];
  const float* bn2b = (const float*)d_in[14];
  const float* Qm   = (const float*)d_in[15];
  const float* Km   = (const float*)d_in[16];
  const float* Vm   = (const float*)d_in[17];
  const float* fc6W = (const float*)d_in[18];
  const float* fc6b = (const float*)d_in[19];
  const float* pv   = (const float*)d_in[20];
  float* ws  = (float*)d_ws;
  float* out = (float*)d_out;

  mega1<<<1365, 256, 0, stream>>>(e1, e2, e3, e4, e5, e6, r_idx, E_w, R_w,
                                  fc6W, fc6b, pv, ws);
  k_bn0gram<<<B, 256, 0, stream>>>(bn0g, bn0b, ws);
  mega2<<<408, 256, 0, stream>>>(Qm, ws);
  mega3<<<4112, 256, 0, stream>>>(Km, Vm, bn2g, bn2b, ws);
  mega4<<<456, 256, 0, stream>>>(ws);
  k_final<<<B, 384, 0, stream>>>(bn1g, bn1b, ws, out);
}